// Round 3
// baseline (124.125 us; speedup 1.0000x reference)
//
#include <hip/hip_runtime.h>
#include <stdint.h>

#define NB 8
#define NN 49104
#define NNP 49152     // NN padded to 192*256
#define NC 90
#define NK 1000
#define KW 16         // ceil(NK/64)
#define CAP2 8192     // candidate capacity in worker LDS
#define NB2 4352      // 4-ULP-wide score bins
#define NB2P 5120     // 1024*5 for chunk-5 prefix scan
#define SBLK 192      // score blocks per image
#define SANCH 256     // anchors per score block
#define NWORK 8       // one worker block per image

typedef unsigned long long u64;

__device__ __forceinline__ void decode_box(const float4 rg, const float4 an,
                                           float W, float H, float* out) {
#pragma clang fp contract(off)
  float l = an.x, t = an.y, r = an.z, bo = an.w;
  float wa = r - l, ha = bo - t;
  float cxa = l + wa * 0.5f, cya = t + ha * 0.5f;
  float cx = cxa + rg.x * wa;
  float cy = cya + rg.y * ha;
  float w = wa * expf(rg.z);
  float h = ha * expf(rg.w);
  float left = cx - w * 0.5f, top = cy - h * 0.5f;
  float right = left + w, botm = top + h;
  out[0] = fminf(fmaxf(left, 0.f), W - 1.f);
  out[1] = fminf(fmaxf(top, 0.f), H - 1.f);
  out[2] = fminf(fmaxf(right, 0.f), W - 1.f);
  out[3] = fminf(fmaxf(botm, 0.f), H - 1.f);
}

// ---- single mega-kernel: score producers + per-image spin-wait workers ----
// Blocks 0..7   : workers (one per image). Spin on score_done[b]==SBLK
//                 (agent-scope acquire), then compact dense keys -> LDS,
//                 counting sort, tie sort, decode, bucketed NMS, writeback.
// Blocks 8..1543: score blocks, image-major. Write dense keys (no atomics),
//                 then __threadfence + agent-scope RELEASE fetch_add on
//                 score_done[img]. Producers never wait -> no deadlock.
// Worker b's tail overlaps score of images b+1.. ; critical path is
// score(all) -> worker7 tail only.
__global__ __launch_bounds__(1024) void k_mega(
    const float* __restrict__ cls, const float* __restrict__ regs,
    const float* __restrict__ anch, const int* __restrict__ isz,
    const int* __restrict__ iszo, const float* __restrict__ sthr_p,
    const float* __restrict__ nthr_p, u64* __restrict__ keys,
    unsigned* __restrict__ score_done, float* __restrict__ out) {
#pragma clang fp contract(off)
  __shared__ __align__(16) char S[151552];
  __shared__ unsigned wsum[16];
  __shared__ int lcnt[NC + 1];
  __shared__ int lofs[NC + 1];
  __shared__ int lcur[NC];
  __shared__ u64 nzv[16];
  __shared__ u64 skeep[KW];
  __shared__ unsigned scnt;

  int tid = threadIdx.x;
  int bid = blockIdx.x;

  if (bid >= NWORK) {
    // ---------------- score producer ----------------
    int sbid = bid - NWORK;
    int b = sbid / SBLK, blk = sbid % SBLK;
    int t0 = blk * SANCH;
    float* lds = (float*)S;
    int acnt = NN - t0; if (acnt > SANCH) acnt = SANCH;
    const float4* src = (const float4*)(cls + ((size_t)b * NN + t0) * NC);
    float4* dst = (float4*)lds;
    int elems4 = acnt * NC / 4;
    for (int t = tid; t < elems4; t += 1024) dst[t] = src[t];
    __syncthreads();
    int a = tid >> 2, q = tid & 3;
    float best = -1e30f; int bc = 0;
    if (a < acnt) {
      for (int c = q; c < NC; c += 4) {
        float v = lds[a * NC + c];
        if (v > best) { best = v; bc = c; }
      }
      float ov; int oc;
      ov = __shfl_xor(best, 1); oc = __shfl_xor(bc, 1);
      if (ov > best || (ov == best && oc < bc)) { best = ov; bc = oc; }
      ov = __shfl_xor(best, 2); oc = __shfl_xor(bc, 2);
      if (ov > best || (ov == best && oc < bc)) { best = ov; bc = oc; }
    }
    if (q == 0) {
      unsigned idx = (unsigned)(t0 + a);
      u64 key = 0ULL;
      if (a < acnt && best >= *sthr_p)
        key = ((u64)__float_as_uint(best) << 32) |
              ((u64)(0xFFFFu - idx) << 16) | (u64)(unsigned)bc;
      keys[(size_t)b * NNP + idx] = key;   // pad slots get 0
    }
    __syncthreads();   // drains vmcnt: all block stores complete
    if (tid == 0) {
      __threadfence();  // agent-scope fence (L2 writeback) before release
      __hip_atomic_fetch_add(&score_done[b], 1u, __ATOMIC_RELEASE,
                             __HIP_MEMORY_SCOPE_AGENT);
    }
    return;
  }

  // ---------------- worker (one block per image) ----------------
  int b = bid;
  u64* cand = (u64*)S;                       // [0, 65536)
  u64* outk = (u64*)(S + 65536);             // [65536, 131072)
  unsigned* hist = (unsigned*)(S + 131072);  // [131072, 151552)
  int lane = tid & 63, wid = tid >> 6;

  // zero hist while scores are still being produced
  for (int i = tid; i < NB2P; i += 1024) hist[i] = 0u;
  if (tid == 0) scnt = 0u;
  __syncthreads();

  if (tid == 0) {
    while (__hip_atomic_load(&score_done[b], __ATOMIC_ACQUIRE,
                             __HIP_MEMORY_SCOPE_AGENT) < SBLK)
      __builtin_amdgcn_s_sleep(2);
  }
  __syncthreads();

  // compact dense keys -> LDS cand[] + histogram (ballot aggregation,
  // LDS atomics only). Order nondeterminism resolved by the full sort.
  {
    const u64* srcp = keys + (size_t)b * NNP;
    u64 lmask = (1ULL << lane) - 1ULL;
    for (int base = 0; base < 48; base += 8) {
      u64 kk[8];
#pragma unroll
      for (int j = 0; j < 8; j++) kk[j] = srcp[(base + j) * 1024 + tid];
#pragma unroll
      for (int j = 0; j < 8; j++) {
        u64 key = kk[j];
        bool valid = key != 0ULL;
        u64 m = __ballot(valid);
        if (m) {
          int leader = (int)__ffsll((unsigned long long)m) - 1;
          unsigned bpos = 0;
          if (lane == leader) bpos = atomicAdd(&scnt, (unsigned)__popcll(m));
          bpos = __shfl(bpos, leader);
          if (valid) {
            unsigned pos = bpos + (unsigned)__popcll(m & lmask);
            if (pos < CAP2) cand[pos] = key;
            unsigned bin = (0x3F800000u - (unsigned)(key >> 32) - 1u) >> 2;
            if (bin >= NB2) bin = NB2 - 1;
            atomicAdd(&hist[bin], 1u);
          }
        }
      }
    }
  }
  __syncthreads();
  unsigned total = scnt; if (total > CAP2) total = CAP2;

  // exclusive prefix scan: 5 bins/thread, wave scan + cross-wave scan
  int base5 = tid * 5;
  unsigned mysum = 0;
#pragma unroll
  for (int i = 0; i < 5; i++) mysum += hist[base5 + i];
  unsigned v = mysum;
  for (int d = 1; d < 64; d <<= 1) {
    unsigned o = __shfl_up(v, d);
    if (lane >= d) v += o;
  }
  if (lane == 63) wsum[wid] = v;
  __syncthreads();
  if (tid == 0) {
    unsigned acc = 0;
    for (int w2 = 0; w2 < 16; w2++) { unsigned c = wsum[w2]; wsum[w2] = acc; acc += c; }
  }
  __syncthreads();
  unsigned running = wsum[wid] + v - mysum;
#pragma unroll
  for (int i = 0; i < 5; i++) {
    unsigned c = hist[base5 + i];
    hist[base5 + i] = running;
    running += c;
  }
  __syncthreads();

  // scatter into bin slots
  for (unsigned p = tid; p < total; p += 1024) {
    u64 key = cand[p];
    unsigned bin = (0x3F800000u - (unsigned)(key >> 32) - 1u) >> 2;
    if (bin >= NB2) bin = NB2 - 1;
    unsigned pos = atomicAdd(&hist[bin], 1u);
    if (pos < CAP2) outk[pos] = key;
  }
  __syncthreads();

  // insertion sort ties within each bin (full u64 key -> deterministic order)
  for (int bin = tid; bin < NB2; bin += 1024) {
    unsigned hi = hist[bin];
    unsigned lo = bin ? hist[bin - 1] : 0u;
    if (hi > CAP2) hi = CAP2;
    if (lo > CAP2) lo = CAP2;
    if (hi > lo + 1) {
      for (unsigned i2 = lo + 1; i2 < hi; i2++) {
        u64 kx = outk[i2];
        int j = (int)i2 - 1;
        while (j >= (int)lo && outk[j] < kx) { outk[j + 1] = outk[j]; j--; }
        outk[j + 1] = kx;
      }
    }
  }
  __syncthreads();

  // ---- phase B: decode top-n, then NMS over the same LDS ----
  int n = (int)total; if (n > NK) n = NK;
  float4* bo = (float4*)S;                              // [0, 16000)
  unsigned short* llab = (unsigned short*)(S + 16000);  // [16000, 18000)
  unsigned short* sidx = (unsigned short*)(S + 18000);  // [18000, 20000)
  unsigned short* send = (unsigned short*)(S + 20000);  // [20000, 22000)
  u64* sm = (u64*)(S + 22016);                          // [22016, 150016)

  float H = (float)isz[b * 2 + 0];
  float W = (float)isz[b * 2 + 1];
  float scale = (float)iszo[b * 2 + 0] / H;
  float offmul = fmaxf(W, H) + 1.0f;
  for (int k = tid; k < n; k += 1024) {
    u64 key = outk[k];
    float sc = __uint_as_float((unsigned)(key >> 32));
    unsigned idx = 0xFFFFu - (unsigned)((key >> 16) & 0xFFFFull);
    int lab = (int)(key & 0xFFFFull);
    float raw[4];
    float4 rg = ((const float4*)regs)[(size_t)b * NN + idx];
    float4 an = ((const float4*)anch)[idx];
    decode_box(rg, an, W, H, raw);
    float off = (float)lab * offmul;
    bo[k] = make_float4(raw[0] + off, raw[1] + off, raw[2] + off, raw[3] + off);
    llab[k] = (unsigned short)lab;
    int g = b * NK + k;
    float* o5 = out + (size_t)g * 5;
    o5[0] = raw[0] * scale; o5[1] = raw[1] * scale;
    o5[2] = raw[2] * scale; o5[3] = raw[3] * scale;
    o5[4] = sc;
    out[(size_t)NB * NK * 5 + g] = (float)lab;
  }
  __syncthreads();  // outk/hist fully consumed; sm may now overwrite them

  for (int t = tid; t < NK * KW; t += 1024) sm[t] = 0ULL;
  if (tid < 16) nzv[tid] = 0ULL;
  if (tid <= NC) lcnt[tid] = 0;
  __syncthreads();

  // bucket by label
  for (int k = tid; k < n; k += 1024) atomicAdd(&lcnt[(int)llab[k]], 1);
  __syncthreads();
  if (tid == 0) {
    int acc = 0;
    for (int c = 0; c < NC; c++) { lofs[c] = acc; acc += lcnt[c]; }
    lofs[NC] = acc;
  }
  __syncthreads();
  if (tid < NC) lcur[tid] = lofs[tid];
  __syncthreads();
  for (int k = tid; k < n; k += 1024) {
    int lab = (int)llab[k];
    int pos = atomicAdd(&lcur[lab], 1);
    sidx[pos] = (unsigned short)k;
    send[pos] = (unsigned short)lofs[lab + 1];
  }
  __syncthreads();

  // same-label pair IoU -> sparse LDS mask bits
  float thr = *nthr_p;
  for (int p = tid; p < n; p += 1024) {
    int e = (int)send[p];
    int a = (int)sidx[p];
    for (int q2 = p + 1; q2 < e; q2++) {
      int c2 = (int)sidx[q2];
      int i = a < c2 ? a : c2;
      int j = a < c2 ? c2 : a;
      float4 Bb = bo[i];
      float4 Cc = bo[j];
      float x0 = Bb.x, y0 = Bb.y, x1 = Bb.z, y1 = Bb.w;
      float ai = (x1 - x0) * (y1 - y0);
      float aj = (Cc.z - Cc.x) * (Cc.w - Cc.y);
      float ltx = fmaxf(x0, Cc.x), lty = fmaxf(y0, Cc.y);
      float rbx = fminf(x1, Cc.z), rby = fminf(y1, Cc.w);
      float ww = fmaxf(rbx - ltx, 0.f), hh = fmaxf(rby - lty, 0.f);
      float inter = ww * hh;
      float den = ((ai + aj) - inter) + 1e-9f;
      float iou = inter / den;
      if (iou > thr) {
        atomicOr(&sm[(size_t)i * KW + (j >> 6)], 1ULL << (j & 63));
        atomicOr(&nzv[i >> 6], 1ULL << (i & 63));
      }
    }
  }
  __syncthreads();

  // restrict nz to valid rows
  if (tid < 16) {
    int base = tid * 64;
    u64 validw;
    if (n <= base) validw = 0ULL;
    else if (n >= base + 64) validw = ~0ULL;
    else validw = (~0ULL) >> (64 - (n - base));
    nzv[tid] &= validw;
  }
  __syncthreads();

  // sparse greedy chain (wave 0; lane w < 16 authoritative for word w)
  int ml = tid & 15;
  if (tid < 64) {
    int bb2 = ml * 64;
    u64 rem;
    if (n <= bb2) rem = ~0ULL;
    else if (n >= bb2 + 64) rem = 0ULL;
    else rem = (~0ULL) << (n - bb2);
    for (int w = 0; w < 16; w++) {
      unsigned rl = (unsigned)__builtin_amdgcn_readlane((int)(unsigned)rem, w);
      unsigned rh = (unsigned)__builtin_amdgcn_readlane((int)(unsigned)(rem >> 32), w);
      u64 rw = ((u64)rh << 32) | (u64)rl;
      u64 active = nzv[w] & ~rw;
      while (active) {
        int i = (int)__ffsll((unsigned long long)active) - 1;
        active &= active - 1ULL;
        u64 crow = sm[(size_t)(w * 64 + i) * KW + ml];
        rem |= crow;
        unsigned cl = (unsigned)__builtin_amdgcn_readlane((int)(unsigned)crow, w);
        unsigned ch = (unsigned)__builtin_amdgcn_readlane((int)(unsigned)(crow >> 32), w);
        rw |= ((u64)ch << 32) | (u64)cl;
        active &= ~rw;
      }
      if (lane == 0) skeep[w] = ~rw;
    }
  }
  __syncthreads();

  for (int k = tid; k < NK; k += 1024) {
    int g = b * NK + k;
    int keep = (int)((skeep[k >> 6] >> (k & 63)) & 1ULL);
    if (keep) {
      out[(size_t)NB * NK * 6 + g] = 1.0f;
    } else {
      float* o5 = out + (size_t)g * 5;
      o5[0] = 0.f; o5[1] = 0.f; o5[2] = 0.f; o5[3] = 0.f; o5[4] = 0.f;
      out[(size_t)NB * NK * 5 + g] = -1.0f;
      out[(size_t)NB * NK * 6 + g] = 0.0f;
    }
  }
}

extern "C" void kernel_launch(void* const* d_in, const int* in_sizes, int n_in,
                              void* d_out, int out_size, void* d_ws, size_t ws_size,
                              hipStream_t stream) {
  const float* cls = (const float*)d_in[0];
  const float* regs = (const float*)d_in[1];
  const float* anch = (const float*)d_in[2];
  const int* isz = (const int*)d_in[3];
  const int* iszo = (const int*)d_in[4];
  const float* sthr = (const float*)d_in[5];
  const float* nthr = (const float*)d_in[6];
  float* out = (float*)d_out;

  char* p = (char*)d_ws;
  auto alloc = [&](size_t bytes) {
    char* r = p;
    p += (bytes + 255) & ~(size_t)255;
    return r;
  };
  u64* keys = (u64*)alloc((size_t)NB * NNP * 8);          // 3.15 MB
  unsigned* score_done = (unsigned*)alloc((size_t)NB * 4);

  hipMemsetAsync(score_done, 0, (size_t)NB * sizeof(unsigned), stream);
  hipLaunchKernelGGL(k_mega, dim3(NWORK + NB * SBLK), dim3(1024), 0, stream,
                     cls, regs, anch, isz, iszo, sthr, nthr,
                     keys, score_done, out);
}

// Round 4
// 119.049 us; speedup vs baseline: 1.0426x; 1.0426x over previous
//
#include <hip/hip_runtime.h>
#include <stdint.h>

#define NB 8
#define NN 49104
#define NNP 49152     // NN padded to 768*64
#define NC 90
#define NK 1000
#define CAP2 8192     // candidate capacity in worker LDS
#define NB2 4352      // 4-ULP-wide score bins
#define NB2P 5120     // 1024*5 for chunk-5 prefix scan

typedef unsigned long long u64;

// ---- per-anchor max/argmax + dense key write (NO global atomics) ----
// key = (score_bits << 32) | ((0xFFFF - idx) << 16) | label ; 0 = invalid/pad
__global__ void k_score(const float* __restrict__ cls,
                        const float* __restrict__ thr_p,
                        u64* __restrict__ keys) {
  __shared__ float lds[64 * NC];
  int b = blockIdx.y;
  int t0 = blockIdx.x * 64;
  int acnt = NN - t0; if (acnt > 64) acnt = 64;
  const float4* src = (const float4*)(cls + ((size_t)b * NN + t0) * NC);
  float4* dst = (float4*)lds;
  int elems4 = acnt * NC / 4;
  for (int t = threadIdx.x; t < elems4; t += 256) dst[t] = src[t];
  __syncthreads();
  int a = threadIdx.x >> 2, q = threadIdx.x & 3;
  float best = -1e30f; int bc = 0;
  if (a < acnt) {
    for (int c = q; c < NC; c += 4) {
      float v = lds[a * NC + c];
      if (v > best) { best = v; bc = c; }
    }
    float ov; int oc;
    ov = __shfl_xor(best, 1); oc = __shfl_xor(bc, 1);
    if (ov > best || (ov == best && oc < bc)) { best = ov; bc = oc; }
    ov = __shfl_xor(best, 2); oc = __shfl_xor(bc, 2);
    if (ov > best || (ov == best && oc < bc)) { best = ov; bc = oc; }
  }
  if (q == 0) {
    unsigned idx = (unsigned)(t0 + a);
    u64 key = 0ULL;
    if (a < acnt && best >= *thr_p)
      key = ((u64)__float_as_uint(best) << 32) |
            ((u64)(0xFFFFu - idx) << 16) | (u64)(unsigned)bc;
    keys[(size_t)b * NNP + idx] = key;   // pad slots get 0
  }
}

__device__ __forceinline__ void decode_box(const float4 rg, const float4 an,
                                           float W, float H, float* out) {
#pragma clang fp contract(off)
  float l = an.x, t = an.y, r = an.z, bo = an.w;
  float wa = r - l, ha = bo - t;
  float cxa = l + wa * 0.5f, cya = t + ha * 0.5f;
  float cx = cxa + rg.x * wa;
  float cy = cya + rg.y * ha;
  float w = wa * expf(rg.z);
  float h = ha * expf(rg.w);
  float left = cx - w * 0.5f, top = cy - h * 0.5f;
  float right = left + w, botm = top + h;
  out[0] = fminf(fmaxf(left, 0.f), W - 1.f);
  out[1] = fminf(fmaxf(top, 0.f), H - 1.f);
  out[2] = fminf(fmaxf(right, 0.f), W - 1.f);
  out[3] = fminf(fmaxf(botm, 0.f), H - 1.f);
}

// ---- fused worker: dense-scan compact + counting sort + tie sort +
//      decode + PER-CLASS greedy NMS + writeback. One block per image. ----
// Cross-class IoU is exactly 0 (class offset 513 > max box extent 511,
// clip makes inter exactly 0), so the reference's global greedy over the
// sorted list decomposes EXACTLY into independent per-class greedy passes
// in the same order. One thread per class (~11 boxes avg), byte live[]
// flags, verbatim IoU expression with i<j operand order -> bit-exact.
__global__ __launch_bounds__(1024) void k_worker(
    const u64* __restrict__ keys,
    const float* __restrict__ regs, const float* __restrict__ anch,
    const int* __restrict__ isz, const int* __restrict__ iszo,
    const float* __restrict__ nthr_p, float* __restrict__ out) {
#pragma clang fp contract(off)
  __shared__ __align__(16) char S[151552];
  __shared__ unsigned wsum[16];
  __shared__ unsigned scnt;
  __shared__ int lcnt[NC + 1];
  __shared__ int lofs[NC + 1];
  __shared__ int lcur[NC];

  u64* cand = (u64*)S;                       // [0, 65536)       (phase A)
  u64* outk = (u64*)(S + 65536);             // [65536, 131072)
  unsigned* hist = (unsigned*)(S + 131072);  // [131072, 151552)

  int tid = threadIdx.x;
  int lane = tid & 63, wid = tid >> 6;
  int b = blockIdx.x;

  for (int i = tid; i < NB2P; i += 1024) hist[i] = 0u;
  if (tid == 0) scnt = 0u;
  if (tid <= NC) lcnt[tid] = 0;
  __syncthreads();

  // dense-scan compaction: 49152 slots -> LDS cand[] + histogram.
  // Ballot aggregation, LDS atomics only (verified in r3).
  {
    const u64* srcp = keys + (size_t)b * NNP;
    u64 lmask = (1ULL << lane) - 1ULL;
    for (int base = 0; base < 48; base += 8) {
      u64 kk[8];
#pragma unroll
      for (int j = 0; j < 8; j++) kk[j] = srcp[(base + j) * 1024 + tid];
#pragma unroll
      for (int j = 0; j < 8; j++) {
        u64 key = kk[j];
        bool valid = key != 0ULL;
        u64 m = __ballot(valid);
        if (m) {
          int leader = (int)__ffsll((unsigned long long)m) - 1;
          unsigned bpos = 0;
          if (lane == leader) bpos = atomicAdd(&scnt, (unsigned)__popcll(m));
          bpos = __shfl(bpos, leader);
          if (valid) {
            unsigned pos = bpos + (unsigned)__popcll(m & lmask);
            if (pos < CAP2) cand[pos] = key;
            unsigned bin = (0x3F800000u - (unsigned)(key >> 32) - 1u) >> 2;
            if (bin >= NB2) bin = NB2 - 1;
            atomicAdd(&hist[bin], 1u);
          }
        }
      }
    }
  }
  __syncthreads();
  unsigned total = scnt; if (total > CAP2) total = CAP2;

  // exclusive prefix scan: 5 bins/thread, wave scan + cross-wave scan
  int base5 = tid * 5;
  unsigned mysum = 0;
#pragma unroll
  for (int i = 0; i < 5; i++) mysum += hist[base5 + i];
  unsigned v = mysum;
  for (int d = 1; d < 64; d <<= 1) {
    unsigned o = __shfl_up(v, d);
    if (lane >= d) v += o;
  }
  if (lane == 63) wsum[wid] = v;
  __syncthreads();
  if (tid == 0) {
    unsigned acc = 0;
    for (int w2 = 0; w2 < 16; w2++) { unsigned c = wsum[w2]; wsum[w2] = acc; acc += c; }
  }
  __syncthreads();
  unsigned running = wsum[wid] + v - mysum;
#pragma unroll
  for (int i = 0; i < 5; i++) {
    unsigned c = hist[base5 + i];
    hist[base5 + i] = running;
    running += c;
  }
  __syncthreads();

  // scatter into bin slots
  for (unsigned p = tid; p < total; p += 1024) {
    u64 key = cand[p];
    unsigned bin = (0x3F800000u - (unsigned)(key >> 32) - 1u) >> 2;
    if (bin >= NB2) bin = NB2 - 1;
    unsigned pos = atomicAdd(&hist[bin], 1u);
    if (pos < CAP2) outk[pos] = key;
  }
  __syncthreads();

  // insertion sort ties within each bin (full u64 key -> deterministic order)
  for (int bin = tid; bin < NB2; bin += 1024) {
    unsigned hi = hist[bin];
    unsigned lo = bin ? hist[bin - 1] : 0u;
    if (hi > CAP2) hi = CAP2;
    if (lo > CAP2) lo = CAP2;
    if (hi > lo + 1) {
      for (unsigned i2 = lo + 1; i2 < hi; i2++) {
        u64 kx = outk[i2];
        int j = (int)i2 - 1;
        while (j >= (int)lo && outk[j] < kx) { outk[j + 1] = outk[j]; j--; }
        outk[j + 1] = kx;
      }
    }
  }
  __syncthreads();

  // ---- phase B: decode top-n, then per-class NMS over overlaid LDS ----
  int n = (int)total; if (n > NK) n = NK;
  float4* bo = (float4*)S;                              // [0, 16000)
  unsigned short* llab = (unsigned short*)(S + 16000);  // [16000, 18000)
  unsigned short* sidx = (unsigned short*)(S + 18000);  // [18000, 20000)
  unsigned char* live = (unsigned char*)(S + 20000);    // [20000, 21000)
  // (all within dead cand[] region; outk/hist untouched until consumed)

  float H = (float)isz[b * 2 + 0];
  float W = (float)isz[b * 2 + 1];
  float scale = (float)iszo[b * 2 + 0] / H;
  float offmul = fmaxf(W, H) + 1.0f;
  for (int k = tid; k < n; k += 1024) {
    u64 key = outk[k];
    float sc = __uint_as_float((unsigned)(key >> 32));
    unsigned idx = 0xFFFFu - (unsigned)((key >> 16) & 0xFFFFull);
    int lab = (int)(key & 0xFFFFull);
    float raw[4];
    float4 rg = ((const float4*)regs)[(size_t)b * NN + idx];
    float4 an = ((const float4*)anch)[idx];
    decode_box(rg, an, W, H, raw);
    float off = (float)lab * offmul;
    bo[k] = make_float4(raw[0] + off, raw[1] + off, raw[2] + off, raw[3] + off);
    llab[k] = (unsigned short)lab;
    live[k] = 1;
    int g = b * NK + k;
    float* o5 = out + (size_t)g * 5;
    o5[0] = raw[0] * scale; o5[1] = raw[1] * scale;
    o5[2] = raw[2] * scale; o5[3] = raw[3] * scale;
    o5[4] = sc;
    out[(size_t)NB * NK * 5 + g] = (float)lab;
  }
  __syncthreads();

  // bucket by label
  for (int k = tid; k < n; k += 1024) atomicAdd(&lcnt[(int)llab[k]], 1);
  __syncthreads();
  if (tid == 0) {
    int acc = 0;
    for (int c = 0; c < NC; c++) { lofs[c] = acc; acc += lcnt[c]; }
    lofs[NC] = acc;
  }
  __syncthreads();
  if (tid < NC) lcur[tid] = lofs[tid];
  __syncthreads();
  for (int k = tid; k < n; k += 1024) {
    int lab = (int)llab[k];
    int pos = atomicAdd(&lcur[lab], 1);
    sidx[pos] = (unsigned short)k;
  }
  __syncthreads();

  // per-class greedy NMS: one thread per class, score-descending order
  float thr = *nthr_p;
  if (tid < NC) {
    int s = lofs[tid], e = lofs[tid + 1];
    // sort bucket ascending by k (= descending score, the global order)
    for (int i = s + 1; i < e; i++) {
      unsigned short x = sidx[i]; int j = i - 1;
      while (j >= s && sidx[j] > x) { sidx[j + 1] = sidx[j]; j--; }
      sidx[j + 1] = x;
    }
    for (int i = s; i < e; i++) {
      int ki = (int)sidx[i];
      if (!live[ki]) continue;
      float4 Bb = bo[ki];
      float x0 = Bb.x, y0 = Bb.y, x1 = Bb.z, y1 = Bb.w;
      float ai = (x1 - x0) * (y1 - y0);
      for (int j = i + 1; j < e; j++) {
        int kj = (int)sidx[j];
        if (!live[kj]) continue;
        float4 Cc = bo[kj];
        float aj = (Cc.z - Cc.x) * (Cc.w - Cc.y);
        float ltx = fmaxf(x0, Cc.x), lty = fmaxf(y0, Cc.y);
        float rbx = fminf(x1, Cc.z), rby = fminf(y1, Cc.w);
        float ww = fmaxf(rbx - ltx, 0.f), hh = fmaxf(rby - lty, 0.f);
        float inter = ww * hh;
        float den = ((ai + aj) - inter) + 1e-9f;
        float iou = inter / den;
        if (iou > thr) live[kj] = 0;
      }
    }
  }
  __syncthreads();

  for (int k = tid; k < NK; k += 1024) {
    int g = b * NK + k;
    int keep = (k < n) ? (int)live[k] : 0;
    if (keep) {
      out[(size_t)NB * NK * 6 + g] = 1.0f;
    } else {
      float* o5 = out + (size_t)g * 5;
      o5[0] = 0.f; o5[1] = 0.f; o5[2] = 0.f; o5[3] = 0.f; o5[4] = 0.f;
      out[(size_t)NB * NK * 5 + g] = -1.0f;
      out[(size_t)NB * NK * 6 + g] = 0.0f;
    }
  }
}

extern "C" void kernel_launch(void* const* d_in, const int* in_sizes, int n_in,
                              void* d_out, int out_size, void* d_ws, size_t ws_size,
                              hipStream_t stream) {
  const float* cls = (const float*)d_in[0];
  const float* regs = (const float*)d_in[1];
  const float* anch = (const float*)d_in[2];
  const int* isz = (const int*)d_in[3];
  const int* iszo = (const int*)d_in[4];
  const float* sthr = (const float*)d_in[5];
  const float* nthr = (const float*)d_in[6];
  float* out = (float*)d_out;

  char* p = (char*)d_ws;
  auto alloc = [&](size_t bytes) {
    char* r = p;
    p += (bytes + 255) & ~(size_t)255;
    return r;
  };
  u64* keys = (u64*)alloc((size_t)NB * NNP * 8);       // 3.15 MB

  hipLaunchKernelGGL(k_score, dim3(NNP / 64, NB), dim3(256), 0, stream,
                     cls, sthr, keys);
  hipLaunchKernelGGL(k_worker, dim3(NB), dim3(1024), 0, stream,
                     keys, regs, anch, isz, iszo, nthr, out);
}

// Round 5
// 113.671 us; speedup vs baseline: 1.0920x; 1.0473x over previous
//
#include <hip/hip_runtime.h>
#include <stdint.h>

#define NB 8
#define NN 49104
#define NNP 49152     // NN padded to 8*6144
#define NC 90
#define NK 1000
#define CAP2 8192     // 8 segments x 1024
#define SEG 1024
#define CHUNK 6144    // NNP / 8
#define NB2 4352      // 4-ULP-wide score bins
#define NB2P 5120     // 1024*5 for chunk-5 prefix scan

typedef unsigned long long u64;

// ---- per-anchor max/argmax + dense key write (NO global atomics) ----
// key = (score_bits << 32) | ((0xFFFF - idx) << 16) | label ; 0 = invalid/pad
__global__ void k_score(const float* __restrict__ cls,
                        const float* __restrict__ thr_p,
                        u64* __restrict__ keys) {
  __shared__ float lds[64 * NC];
  int b = blockIdx.y;
  int t0 = blockIdx.x * 64;
  int acnt = NN - t0; if (acnt > 64) acnt = 64;
  const float4* src = (const float4*)(cls + ((size_t)b * NN + t0) * NC);
  float4* dst = (float4*)lds;
  int elems4 = acnt * NC / 4;
  for (int t = threadIdx.x; t < elems4; t += 256) dst[t] = src[t];
  __syncthreads();
  int a = threadIdx.x >> 2, q = threadIdx.x & 3;
  float best = -1e30f; int bc = 0;
  if (a < acnt) {
    for (int c = q; c < NC; c += 4) {
      float v = lds[a * NC + c];
      if (v > best) { best = v; bc = c; }
    }
    float ov; int oc;
    ov = __shfl_xor(best, 1); oc = __shfl_xor(bc, 1);
    if (ov > best || (ov == best && oc < bc)) { best = ov; bc = oc; }
    ov = __shfl_xor(best, 2); oc = __shfl_xor(bc, 2);
    if (ov > best || (ov == best && oc < bc)) { best = ov; bc = oc; }
  }
  if (q == 0) {
    unsigned idx = (unsigned)(t0 + a);
    u64 key = 0ULL;
    if (a < acnt && best >= *thr_p)
      key = ((u64)__float_as_uint(best) << 32) |
            ((u64)(0xFFFFu - idx) << 16) | (u64)(unsigned)bc;
    keys[(size_t)b * NNP + idx] = key;   // pad slots get 0
  }
}

// ---- parallel compaction: 8 blocks/image, each owns a 1024-slot segment ----
// Wide (64 blocks): the serialized ballot+LDS-atomic chain is only 6 links
// per block (r4 lesson: 384 links in 8 blocks cost ~40 us). Exact counts out.
__global__ __launch_bounds__(1024) void k_compact(const u64* __restrict__ keys,
                                                  u64* __restrict__ ckeys,
                                                  unsigned* __restrict__ segcnt) {
  __shared__ unsigned scnt;
  int tid = threadIdx.x;
  int lane = tid & 63;
  int b = blockIdx.y, chunk = blockIdx.x;
  if (tid == 0) scnt = 0u;
  __syncthreads();
  const u64* src = keys + (size_t)b * NNP + (size_t)chunk * CHUNK;
  u64* dst = ckeys + (size_t)b * CAP2 + (size_t)chunk * SEG;
  u64 k0 = src[tid], k1 = src[tid + 1024], k2 = src[tid + 2048];
  u64 k3 = src[tid + 3072], k4 = src[tid + 4096], k5 = src[tid + 5120];
  u64 lmask = (1ULL << lane) - 1ULL;
  u64 kk[6] = {k0, k1, k2, k3, k4, k5};
#pragma unroll
  for (int j = 0; j < 6; j++) {
    u64 key = kk[j];
    bool valid = key != 0ULL;
    u64 m = __ballot(valid);
    if (m) {
      int leader = (int)__ffsll((unsigned long long)m) - 1;
      unsigned base = 0;
      if (lane == leader) base = atomicAdd(&scnt, (unsigned)__popcll(m));
      base = __shfl(base, leader);
      if (valid) {
        unsigned pos = base + (unsigned)__popcll(m & lmask);
        if (pos < SEG) dst[pos] = key;
      }
    }
  }
  __syncthreads();
  if (tid == 0) {
    unsigned total = scnt; if (total > SEG) total = SEG;
    segcnt[b * 8 + chunk] = total;
  }
}

__device__ __forceinline__ void decode_box(const float4 rg, const float4 an,
                                           float W, float H, float* out) {
#pragma clang fp contract(off)
  float l = an.x, t = an.y, r = an.z, bo = an.w;
  float wa = r - l, ha = bo - t;
  float cxa = l + wa * 0.5f, cya = t + ha * 0.5f;
  float cx = cxa + rg.x * wa;
  float cy = cya + rg.y * ha;
  float w = wa * expf(rg.z);
  float h = ha * expf(rg.w);
  float left = cx - w * 0.5f, top = cy - h * 0.5f;
  float right = left + w, botm = top + h;
  out[0] = fminf(fmaxf(left, 0.f), W - 1.f);
  out[1] = fminf(fmaxf(top, 0.f), H - 1.f);
  out[2] = fminf(fmaxf(right, 0.f), W - 1.f);
  out[3] = fminf(fmaxf(botm, 0.f), H - 1.f);
}

// ---- fused worker: exact-count gather + counting sort + tie sort +
//      decode + PER-CLASS greedy NMS (r4-verified bit-exact) ----
// One block per image. Phase A LDS: cand|outk|hist (148 KB); phase B
// overlays bo|llab|sidx|live in dead cand region while outk is consumed.
__global__ __launch_bounds__(1024) void k_worker(
    const u64* __restrict__ ckeys, const unsigned* __restrict__ segcnt,
    const float* __restrict__ regs, const float* __restrict__ anch,
    const int* __restrict__ isz, const int* __restrict__ iszo,
    const float* __restrict__ nthr_p, float* __restrict__ out) {
#pragma clang fp contract(off)
  __shared__ __align__(16) char S[151552];
  __shared__ unsigned wsum[16];
  __shared__ unsigned sofs[9];
  __shared__ int lcnt[NC + 1];
  __shared__ int lofs[NC + 1];
  __shared__ int lcur[NC];

  u64* cand = (u64*)S;                       // [0, 65536)
  u64* outk = (u64*)(S + 65536);             // [65536, 131072)
  unsigned* hist = (unsigned*)(S + 131072);  // [131072, 151552)

  int tid = threadIdx.x;
  int lane = tid & 63, wid = tid >> 6;
  int b = blockIdx.x;

  for (int i = tid; i < NB2P; i += 1024) hist[i] = 0u;
  if (tid <= NC) lcnt[tid] = 0;
  if (tid == 0) {
    unsigned acc = 0;
    for (int s = 0; s < 8; s++) {
      unsigned c = segcnt[b * 8 + s]; if (c > SEG) c = SEG;
      sofs[s] = acc; acc += c;
    }
    sofs[8] = acc;
  }
  __syncthreads();
  unsigned total = sofs[8];

  // gather compacted segments contiguous into cand (exact counts, no ballots)
  for (int s = 0; s < 8; s++) {
    unsigned o = sofs[s], c = sofs[s + 1] - o;
    const u64* srcp = ckeys + (size_t)b * CAP2 + (size_t)s * SEG;
    for (unsigned i = tid; i < c; i += 1024) cand[o + i] = srcp[i];
  }
  __syncthreads();

  // histogram over 4-ULP score bins
  for (unsigned p = tid; p < total; p += 1024) {
    unsigned bin = (0x3F800000u - (unsigned)(cand[p] >> 32) - 1u) >> 2;
    if (bin >= NB2) bin = NB2 - 1;
    atomicAdd(&hist[bin], 1u);
  }
  __syncthreads();

  // exclusive prefix scan: 5 bins/thread, wave scan + cross-wave scan
  int base5 = tid * 5;
  unsigned mysum = 0;
#pragma unroll
  for (int i = 0; i < 5; i++) mysum += hist[base5 + i];
  unsigned v = mysum;
  for (int d = 1; d < 64; d <<= 1) {
    unsigned o = __shfl_up(v, d);
    if (lane >= d) v += o;
  }
  if (lane == 63) wsum[wid] = v;
  __syncthreads();
  if (tid == 0) {
    unsigned acc = 0;
    for (int w2 = 0; w2 < 16; w2++) { unsigned c = wsum[w2]; wsum[w2] = acc; acc += c; }
  }
  __syncthreads();
  unsigned running = wsum[wid] + v - mysum;
#pragma unroll
  for (int i = 0; i < 5; i++) {
    unsigned c = hist[base5 + i];
    hist[base5 + i] = running;
    running += c;
  }
  __syncthreads();

  // scatter into bin slots
  for (unsigned p = tid; p < total; p += 1024) {
    u64 key = cand[p];
    unsigned bin = (0x3F800000u - (unsigned)(key >> 32) - 1u) >> 2;
    if (bin >= NB2) bin = NB2 - 1;
    unsigned pos = atomicAdd(&hist[bin], 1u);
    if (pos < CAP2) outk[pos] = key;
  }
  __syncthreads();

  // insertion sort ties within each bin (full u64 key -> deterministic order)
  for (int bin = tid; bin < NB2; bin += 1024) {
    unsigned hi = hist[bin];
    unsigned lo = bin ? hist[bin - 1] : 0u;
    if (hi > CAP2) hi = CAP2;
    if (lo > CAP2) lo = CAP2;
    if (hi > lo + 1) {
      for (unsigned i2 = lo + 1; i2 < hi; i2++) {
        u64 kx = outk[i2];
        int j = (int)i2 - 1;
        while (j >= (int)lo && outk[j] < kx) { outk[j + 1] = outk[j]; j--; }
        outk[j + 1] = kx;
      }
    }
  }
  __syncthreads();

  // ---- phase B: decode top-n, then per-class NMS over overlaid LDS ----
  int n = (int)total; if (n > NK) n = NK;
  float4* bo = (float4*)S;                              // [0, 16000)
  unsigned short* llab = (unsigned short*)(S + 16000);  // [16000, 18000)
  unsigned short* sidx = (unsigned short*)(S + 18000);  // [18000, 20000)
  unsigned char* live = (unsigned char*)(S + 20000);    // [20000, 21000)
  // (all within dead cand[] region; outk read-only until consumed, hist dead)

  float H = (float)isz[b * 2 + 0];
  float W = (float)isz[b * 2 + 1];
  float scale = (float)iszo[b * 2 + 0] / H;
  float offmul = fmaxf(W, H) + 1.0f;
  for (int k = tid; k < n; k += 1024) {
    u64 key = outk[k];
    float sc = __uint_as_float((unsigned)(key >> 32));
    unsigned idx = 0xFFFFu - (unsigned)((key >> 16) & 0xFFFFull);
    int lab = (int)(key & 0xFFFFull);
    float raw[4];
    float4 rg = ((const float4*)regs)[(size_t)b * NN + idx];
    float4 an = ((const float4*)anch)[idx];
    decode_box(rg, an, W, H, raw);
    float off = (float)lab * offmul;
    bo[k] = make_float4(raw[0] + off, raw[1] + off, raw[2] + off, raw[3] + off);
    llab[k] = (unsigned short)lab;
    live[k] = 1;
    int g = b * NK + k;
    float* o5 = out + (size_t)g * 5;
    o5[0] = raw[0] * scale; o5[1] = raw[1] * scale;
    o5[2] = raw[2] * scale; o5[3] = raw[3] * scale;
    o5[4] = sc;
    out[(size_t)NB * NK * 5 + g] = (float)lab;
  }
  __syncthreads();

  // bucket by label
  for (int k = tid; k < n; k += 1024) atomicAdd(&lcnt[(int)llab[k]], 1);
  __syncthreads();
  if (tid == 0) {
    int acc = 0;
    for (int c = 0; c < NC; c++) { lofs[c] = acc; acc += lcnt[c]; }
    lofs[NC] = acc;
  }
  __syncthreads();
  if (tid < NC) lcur[tid] = lofs[tid];
  __syncthreads();
  for (int k = tid; k < n; k += 1024) {
    int lab = (int)llab[k];
    int pos = atomicAdd(&lcur[lab], 1);
    sidx[pos] = (unsigned short)k;
  }
  __syncthreads();

  // per-class greedy NMS: one thread per class, score-descending order.
  // Cross-class IoU is exactly 0 (offset 513 > extent 511, clip -> inter 0),
  // so global greedy decomposes exactly. Verbatim IoU, i<j order -> bit-exact.
  float thr = *nthr_p;
  if (tid < NC) {
    int s = lofs[tid], e = lofs[tid + 1];
    // sort bucket ascending by k (= descending score, the global order)
    for (int i = s + 1; i < e; i++) {
      unsigned short x = sidx[i]; int j = i - 1;
      while (j >= s && sidx[j] > x) { sidx[j + 1] = sidx[j]; j--; }
      sidx[j + 1] = x;
    }
    for (int i = s; i < e; i++) {
      int ki = (int)sidx[i];
      if (!live[ki]) continue;
      float4 Bb = bo[ki];
      float x0 = Bb.x, y0 = Bb.y, x1 = Bb.z, y1 = Bb.w;
      float ai = (x1 - x0) * (y1 - y0);
      for (int j = i + 1; j < e; j++) {
        int kj = (int)sidx[j];
        if (!live[kj]) continue;
        float4 Cc = bo[kj];
        float aj = (Cc.z - Cc.x) * (Cc.w - Cc.y);
        float ltx = fmaxf(x0, Cc.x), lty = fmaxf(y0, Cc.y);
        float rbx = fminf(x1, Cc.z), rby = fminf(y1, Cc.w);
        float ww = fmaxf(rbx - ltx, 0.f), hh = fmaxf(rby - lty, 0.f);
        float inter = ww * hh;
        float den = ((ai + aj) - inter) + 1e-9f;
        float iou = inter / den;
        if (iou > thr) live[kj] = 0;
      }
    }
  }
  __syncthreads();

  for (int k = tid; k < NK; k += 1024) {
    int g = b * NK + k;
    int keep = (k < n) ? (int)live[k] : 0;
    if (keep) {
      out[(size_t)NB * NK * 6 + g] = 1.0f;
    } else {
      float* o5 = out + (size_t)g * 5;
      o5[0] = 0.f; o5[1] = 0.f; o5[2] = 0.f; o5[3] = 0.f; o5[4] = 0.f;
      out[(size_t)NB * NK * 5 + g] = -1.0f;
      out[(size_t)NB * NK * 6 + g] = 0.0f;
    }
  }
}

extern "C" void kernel_launch(void* const* d_in, const int* in_sizes, int n_in,
                              void* d_out, int out_size, void* d_ws, size_t ws_size,
                              hipStream_t stream) {
  const float* cls = (const float*)d_in[0];
  const float* regs = (const float*)d_in[1];
  const float* anch = (const float*)d_in[2];
  const int* isz = (const int*)d_in[3];
  const int* iszo = (const int*)d_in[4];
  const float* sthr = (const float*)d_in[5];
  const float* nthr = (const float*)d_in[6];
  float* out = (float*)d_out;

  char* p = (char*)d_ws;
  auto alloc = [&](size_t bytes) {
    char* r = p;
    p += (bytes + 255) & ~(size_t)255;
    return r;
  };
  u64* keys = (u64*)alloc((size_t)NB * NNP * 8);       // 3.15 MB
  u64* ckeys = (u64*)alloc((size_t)NB * CAP2 * 8);     // 512 KB
  unsigned* segcnt = (unsigned*)alloc((size_t)NB * 8 * 4);

  hipLaunchKernelGGL(k_score, dim3(NNP / 64, NB), dim3(256), 0, stream,
                     cls, sthr, keys);
  hipLaunchKernelGGL(k_compact, dim3(8, NB), dim3(1024), 0, stream,
                     keys, ckeys, segcnt);
  hipLaunchKernelGGL(k_worker, dim3(NB), dim3(1024), 0, stream,
                     ckeys, segcnt, regs, anch, isz, iszo, nthr, out);
}

// Round 6
// 58.432 us; speedup vs baseline: 2.1243x; 1.9453x over previous
//
#include <hip/hip_runtime.h>
#include <stdint.h>

#define NB 8
#define NN 49104
#define NNP 49152     // NN padded to 8*6144
#define NC 90
#define NK 1000
#define CAP2 8192     // 8 segments x 1024
#define SEG 1024
#define CHUNK 6144    // NNP / 8
#define NB2 4352      // 4-ULP-wide score bins
#define NB2P 5120     // 1024*5 for chunk-5 prefix scan

typedef unsigned long long u64;

// ---- per-anchor max/argmax + dense key write (NO global atomics) ----
// key = (score_bits << 32) | ((0xFFFF - idx) << 16) | label ; 0 = invalid/pad
__global__ void k_score(const float* __restrict__ cls,
                        const float* __restrict__ thr_p,
                        u64* __restrict__ keys) {
  __shared__ float lds[64 * NC];
  int b = blockIdx.y;
  int t0 = blockIdx.x * 64;
  int acnt = NN - t0; if (acnt > 64) acnt = 64;
  const float4* src = (const float4*)(cls + ((size_t)b * NN + t0) * NC);
  float4* dst = (float4*)lds;
  int elems4 = acnt * NC / 4;
  for (int t = threadIdx.x; t < elems4; t += 256) dst[t] = src[t];
  __syncthreads();
  int a = threadIdx.x >> 2, q = threadIdx.x & 3;
  float best = -1e30f; int bc = 0;
  if (a < acnt) {
    for (int c = q; c < NC; c += 4) {
      float v = lds[a * NC + c];
      if (v > best) { best = v; bc = c; }
    }
    float ov; int oc;
    ov = __shfl_xor(best, 1); oc = __shfl_xor(bc, 1);
    if (ov > best || (ov == best && oc < bc)) { best = ov; bc = oc; }
    ov = __shfl_xor(best, 2); oc = __shfl_xor(bc, 2);
    if (ov > best || (ov == best && oc < bc)) { best = ov; bc = oc; }
  }
  if (q == 0) {
    unsigned idx = (unsigned)(t0 + a);
    u64 key = 0ULL;
    if (a < acnt && best >= *thr_p)
      key = ((u64)__float_as_uint(best) << 32) |
            ((u64)(0xFFFFu - idx) << 16) | (u64)(unsigned)bc;
    keys[(size_t)b * NNP + idx] = key;   // pad slots get 0
  }
}

// ---- parallel compaction: 8 blocks/image, each owns a 1024-slot segment ----
// Wide (64 blocks): serialized ballot+LDS-atomic chain is only 6 links/block.
__global__ __launch_bounds__(1024) void k_compact(const u64* __restrict__ keys,
                                                  u64* __restrict__ ckeys,
                                                  unsigned* __restrict__ segcnt) {
  __shared__ unsigned scnt;
  int tid = threadIdx.x;
  int lane = tid & 63;
  int b = blockIdx.y, chunk = blockIdx.x;
  if (tid == 0) scnt = 0u;
  __syncthreads();
  const u64* src = keys + (size_t)b * NNP + (size_t)chunk * CHUNK;
  u64* dst = ckeys + (size_t)b * CAP2 + (size_t)chunk * SEG;
  u64 k0 = src[tid], k1 = src[tid + 1024], k2 = src[tid + 2048];
  u64 k3 = src[tid + 3072], k4 = src[tid + 4096], k5 = src[tid + 5120];
  u64 lmask = (1ULL << lane) - 1ULL;
  u64 kk[6] = {k0, k1, k2, k3, k4, k5};
#pragma unroll
  for (int j = 0; j < 6; j++) {
    u64 key = kk[j];
    bool valid = key != 0ULL;
    u64 m = __ballot(valid);
    if (m) {
      int leader = (int)__ffsll((unsigned long long)m) - 1;
      unsigned base = 0;
      if (lane == leader) base = atomicAdd(&scnt, (unsigned)__popcll(m));
      base = __shfl(base, leader);
      if (valid) {
        unsigned pos = base + (unsigned)__popcll(m & lmask);
        if (pos < SEG) dst[pos] = key;
      }
    }
  }
  __syncthreads();
  if (tid == 0) {
    unsigned total = scnt; if (total > SEG) total = SEG;
    segcnt[b * 8 + chunk] = total;
  }
}

__device__ __forceinline__ void decode_box(const float4 rg, const float4 an,
                                           float W, float H, float* out) {
#pragma clang fp contract(off)
  float l = an.x, t = an.y, r = an.z, bo = an.w;
  float wa = r - l, ha = bo - t;
  float cxa = l + wa * 0.5f, cya = t + ha * 0.5f;
  float cx = cxa + rg.x * wa;
  float cy = cya + rg.y * ha;
  float w = wa * expf(rg.z);
  float h = ha * expf(rg.w);
  float left = cx - w * 0.5f, top = cy - h * 0.5f;
  float right = left + w, botm = top + h;
  out[0] = fminf(fmaxf(left, 0.f), W - 1.f);
  out[1] = fminf(fmaxf(top, 0.f), H - 1.f);
  out[2] = fminf(fmaxf(right, 0.f), W - 1.f);
  out[3] = fminf(fmaxf(botm, 0.f), H - 1.f);
}

// ---- fused worker: exact-count gather + counting sort + tie sort + decode
//      + per-class NMS with PARALLEL pair-IoU and O(m) register chain ----
// Per-class decomposition is exact (class offset 513 > extent 511 -> cross-
// class IoU == 0; r4/r5 verified absmax 0). r5 lesson: per-lane serial O(m^2)
// LDS loops cost ~70us. Fix: deterministic rank-bucketing (bitmap+popcount,
// no sort), pair IoU computed one-row-per-thread (1024-wide) into u64
// register masks, chain = O(m) dependent LDS reads per class.
__global__ __launch_bounds__(1024) void k_worker(
    const u64* __restrict__ ckeys, const unsigned* __restrict__ segcnt,
    const float* __restrict__ regs, const float* __restrict__ anch,
    const int* __restrict__ isz, const int* __restrict__ iszo,
    const float* __restrict__ nthr_p, float* __restrict__ out) {
#pragma clang fp contract(off)
  __shared__ __align__(16) char S[151552];
  __shared__ unsigned wsum[16];
  __shared__ unsigned sofs[9];
  __shared__ int lcnt[NC];
  __shared__ int lofs[NC + 1];

  u64* cand = (u64*)S;                       // [0, 65536)
  u64* outk = (u64*)(S + 65536);             // [65536, 131072)
  unsigned* hist = (unsigned*)(S + 131072);  // [131072, 151552)

  int tid = threadIdx.x;
  int lane = tid & 63, wid = tid >> 6;
  int b = blockIdx.x;

  for (int i = tid; i < NB2P; i += 1024) hist[i] = 0u;
  if (tid == 0) {
    unsigned acc = 0;
    for (int s = 0; s < 8; s++) {
      unsigned c = segcnt[b * 8 + s]; if (c > SEG) c = SEG;
      sofs[s] = acc; acc += c;
    }
    sofs[8] = acc;
  }
  __syncthreads();
  unsigned total = sofs[8];

  // gather compacted segments contiguous into cand (exact counts, no ballots)
  for (int s = 0; s < 8; s++) {
    unsigned o = sofs[s], c = sofs[s + 1] - o;
    const u64* srcp = ckeys + (size_t)b * CAP2 + (size_t)s * SEG;
    for (unsigned i = tid; i < c; i += 1024) cand[o + i] = srcp[i];
  }
  __syncthreads();

  // histogram over 4-ULP score bins
  for (unsigned p = tid; p < total; p += 1024) {
    unsigned bin = (0x3F800000u - (unsigned)(cand[p] >> 32) - 1u) >> 2;
    if (bin >= NB2) bin = NB2 - 1;
    atomicAdd(&hist[bin], 1u);
  }
  __syncthreads();

  // exclusive prefix scan: 5 bins/thread, wave scan + cross-wave scan
  int base5 = tid * 5;
  unsigned mysum = 0;
#pragma unroll
  for (int i = 0; i < 5; i++) mysum += hist[base5 + i];
  unsigned v = mysum;
  for (int d = 1; d < 64; d <<= 1) {
    unsigned o = __shfl_up(v, d);
    if (lane >= d) v += o;
  }
  if (lane == 63) wsum[wid] = v;
  __syncthreads();
  if (tid == 0) {
    unsigned acc = 0;
    for (int w2 = 0; w2 < 16; w2++) { unsigned c = wsum[w2]; wsum[w2] = acc; acc += c; }
  }
  __syncthreads();
  unsigned running = wsum[wid] + v - mysum;
#pragma unroll
  for (int i = 0; i < 5; i++) {
    unsigned c = hist[base5 + i];
    hist[base5 + i] = running;
    running += c;
  }
  __syncthreads();

  // scatter into bin slots
  for (unsigned p = tid; p < total; p += 1024) {
    u64 key = cand[p];
    unsigned bin = (0x3F800000u - (unsigned)(key >> 32) - 1u) >> 2;
    if (bin >= NB2) bin = NB2 - 1;
    unsigned pos = atomicAdd(&hist[bin], 1u);
    if (pos < CAP2) outk[pos] = key;
  }
  __syncthreads();

  // insertion sort ties within each bin (full u64 key -> deterministic order)
  for (int bin = tid; bin < NB2; bin += 1024) {
    unsigned hi = hist[bin];
    unsigned lo = bin ? hist[bin - 1] : 0u;
    if (hi > CAP2) hi = CAP2;
    if (lo > CAP2) lo = CAP2;
    if (hi > lo + 1) {
      for (unsigned i2 = lo + 1; i2 < hi; i2++) {
        u64 kx = outk[i2];
        int j = (int)i2 - 1;
        while (j >= (int)lo && outk[j] < kx) { outk[j + 1] = outk[j]; j--; }
        outk[j + 1] = kx;
      }
    }
  }
  __syncthreads();

  // ---- phase B: decode top-n + per-class NMS over overlaid LDS ----
  int n = (int)total; if (n > NK) n = NK;
  float4* bo = (float4*)S;                              // [0, 16000)
  unsigned short* llab = (unsigned short*)(S + 16000);  // [16000, 18000)
  unsigned short* sidx = (unsigned short*)(S + 18000);  // [18000, 20000)
  unsigned char* live = (unsigned char*)(S + 20000);    // [20000, 21000)
  u64* clsbits = (u64*)(S + 21008);                     // [21008, 32528) 90x16
  u64* nmsmask = (u64*)(S + 32536);                     // [32536, 78616) 90x64
  // clsbits/bo/llab/sidx/live sit in dead cand[]; nmsmask additionally
  // overlays outk[] but is only written AFTER decode consumed outk.

  float H = (float)isz[b * 2 + 0];
  float W = (float)isz[b * 2 + 1];
  float scale = (float)iszo[b * 2 + 0] / H;
  float offmul = fmaxf(W, H) + 1.0f;
  for (int i = tid; i < NC * 16; i += 1024) clsbits[i] = 0ULL;
  for (int k = tid; k < n; k += 1024) {
    u64 key = outk[k];
    float sc = __uint_as_float((unsigned)(key >> 32));
    unsigned idx = 0xFFFFu - (unsigned)((key >> 16) & 0xFFFFull);
    int lab = (int)(key & 0xFFFFull);
    float raw[4];
    float4 rg = ((const float4*)regs)[(size_t)b * NN + idx];
    float4 an = ((const float4*)anch)[idx];
    decode_box(rg, an, W, H, raw);
    float off = (float)lab * offmul;
    bo[k] = make_float4(raw[0] + off, raw[1] + off, raw[2] + off, raw[3] + off);
    llab[k] = (unsigned short)lab;
    live[k] = 1;
    int g = b * NK + k;
    float* o5 = out + (size_t)g * 5;
    o5[0] = raw[0] * scale; o5[1] = raw[1] * scale;
    o5[2] = raw[2] * scale; o5[3] = raw[3] * scale;
    o5[4] = sc;
    out[(size_t)NB * NK * 5 + g] = (float)lab;
  }
  __syncthreads();  // outk fully consumed; clsbits zeroed

  // per-class membership bitmaps (k ascending == score descending)
  for (int k = tid; k < n; k += 1024)
    atomicOr(&clsbits[(int)llab[k] * 16 + (k >> 6)], 1ULL << (k & 63));
  __syncthreads();

  // class sizes via popcount, then exclusive prefix
  if (tid < NC) {
    unsigned cnt = 0;
#pragma unroll
    for (int w = 0; w < 16; w++) cnt += (unsigned)__popcll(clsbits[tid * 16 + w]);
    lcnt[tid] = (int)cnt;
  }
  __syncthreads();
  if (tid == 0) {
    int acc = 0;
    for (int c = 0; c < NC; c++) { lofs[c] = acc; acc += lcnt[c]; }
    lofs[NC] = acc;
  }
  __syncthreads();

  // deterministic rank placement: sidx buckets sorted ascending k, no sort
  for (int k = tid; k < n; k += 1024) {
    int lab = (int)llab[k];
    const u64* cb = &clsbits[lab * 16];
    int w0 = k >> 6;
    unsigned pos = 0;
    for (int w = 0; w < w0; w++) pos += (unsigned)__popcll(cb[w]);
    pos += (unsigned)__popcll(cb[w0] & ((1ULL << (k & 63)) - 1ULL));
    sidx[lofs[lab] + pos] = (unsigned short)k;
  }
  __syncthreads();

  // pair IoU, one suppression row per thread (1024-wide parallel).
  // sidx[p] < sidx[q] for p<q in a bucket -> verbatim i<j operand order.
  float thr = *nthr_p;
  for (int p = tid; p < n; p += 1024) {
    int ki = (int)sidx[p];
    int lab = (int)llab[ki];
    int s = lofs[lab], e = lofs[lab + 1];
    int r = p - s;
    if (r < 64) {
      u64 mask = 0ULL;
      float4 Bb = bo[ki];
      float x0 = Bb.x, y0 = Bb.y, x1 = Bb.z, y1 = Bb.w;
      float ai = (x1 - x0) * (y1 - y0);
      int qe = e; if (qe > s + 64) qe = s + 64;
      for (int q = p + 1; q < qe; q++) {
        int kj = (int)sidx[q];
        float4 Cc = bo[kj];
        float aj = (Cc.z - Cc.x) * (Cc.w - Cc.y);
        float ltx = fmaxf(x0, Cc.x), lty = fmaxf(y0, Cc.y);
        float rbx = fminf(x1, Cc.z), rby = fminf(y1, Cc.w);
        float ww = fmaxf(rbx - ltx, 0.f), hh = fmaxf(rby - lty, 0.f);
        float inter = ww * hh;
        float den = ((ai + aj) - inter) + 1e-9f;
        float iou = inter / den;
        if (iou > thr) mask |= 1ULL << (q - s);
      }
      nmsmask[lab * 64 + r] = mask;   // row owned by exactly this thread
    }
  }
  __syncthreads();

  // per-class greedy chain: O(m) dependent LDS reads, register rem
  if (tid < NC) {
    int s = lofs[tid], e = lofs[tid + 1], m = e - s;
    if (m <= 64) {
      u64 rem = 0ULL;
      for (int r = 0; r < m; r++)
        if (!((rem >> r) & 1ULL)) rem |= nmsmask[tid * 64 + r];
      for (int r = 0; r < m; r++)
        live[(int)sidx[s + r]] = (unsigned char)(1ULL ^ ((rem >> r) & 1ULL));
    } else {
      // exact fallback (bucket > 64: statistically unreachable here)
      for (int r = 0; r < m; r++) live[(int)sidx[s + r]] = 1;
      for (int i = s; i < e; i++) {
        int ki = (int)sidx[i];
        if (!live[ki]) continue;
        float4 Bb = bo[ki];
        float x0 = Bb.x, y0 = Bb.y, x1 = Bb.z, y1 = Bb.w;
        float ai = (x1 - x0) * (y1 - y0);
        for (int j = i + 1; j < e; j++) {
          int kj = (int)sidx[j];
          if (!live[kj]) continue;
          float4 Cc = bo[kj];
          float aj = (Cc.z - Cc.x) * (Cc.w - Cc.y);
          float ltx = fmaxf(x0, Cc.x), lty = fmaxf(y0, Cc.y);
          float rbx = fminf(x1, Cc.z), rby = fminf(y1, Cc.w);
          float ww = fmaxf(rbx - ltx, 0.f), hh = fmaxf(rby - lty, 0.f);
          float inter = ww * hh;
          float den = ((ai + aj) - inter) + 1e-9f;
          float iou = inter / den;
          if (iou > thr) live[kj] = 0;
        }
      }
    }
  }
  __syncthreads();

  for (int k = tid; k < NK; k += 1024) {
    int g = b * NK + k;
    int keep = (k < n) ? (int)live[k] : 0;
    if (keep) {
      out[(size_t)NB * NK * 6 + g] = 1.0f;
    } else {
      float* o5 = out + (size_t)g * 5;
      o5[0] = 0.f; o5[1] = 0.f; o5[2] = 0.f; o5[3] = 0.f; o5[4] = 0.f;
      out[(size_t)NB * NK * 5 + g] = -1.0f;
      out[(size_t)NB * NK * 6 + g] = 0.0f;
    }
  }
}

extern "C" void kernel_launch(void* const* d_in, const int* in_sizes, int n_in,
                              void* d_out, int out_size, void* d_ws, size_t ws_size,
                              hipStream_t stream) {
  const float* cls = (const float*)d_in[0];
  const float* regs = (const float*)d_in[1];
  const float* anch = (const float*)d_in[2];
  const int* isz = (const int*)d_in[3];
  const int* iszo = (const int*)d_in[4];
  const float* sthr = (const float*)d_in[5];
  const float* nthr = (const float*)d_in[6];
  float* out = (float*)d_out;

  char* p = (char*)d_ws;
  auto alloc = [&](size_t bytes) {
    char* r = p;
    p += (bytes + 255) & ~(size_t)255;
    return r;
  };
  u64* keys = (u64*)alloc((size_t)NB * NNP * 8);       // 3.15 MB
  u64* ckeys = (u64*)alloc((size_t)NB * CAP2 * 8);     // 512 KB
  unsigned* segcnt = (unsigned*)alloc((size_t)NB * 8 * 4);

  hipLaunchKernelGGL(k_score, dim3(NNP / 64, NB), dim3(256), 0, stream,
                     cls, sthr, keys);
  hipLaunchKernelGGL(k_compact, dim3(8, NB), dim3(1024), 0, stream,
                     keys, ckeys, segcnt);
  hipLaunchKernelGGL(k_worker, dim3(NB), dim3(1024), 0, stream,
                     ckeys, segcnt, regs, anch, isz, iszo, nthr, out);
}

// Round 7
// 55.590 us; speedup vs baseline: 2.2329x; 1.0511x over previous
//
#include <hip/hip_runtime.h>
#include <stdint.h>

#define NB 8
#define NN 49104
#define NC 90
#define NK 1000
#define SA 192        // anchors per score block
#define NSEG 256      // score blocks (= key segments) per image; NSEG*SA=49152
#define CAP2 8192     // candidate capacity in worker LDS
#define NB2 4352      // 4-ULP-wide score bins
#define NB2P 5120     // 1024*5 for chunk-5 prefix scan

typedef unsigned long long u64;

// ---- fused score + in-block compaction ----
// key = (score_bits << 32) | ((0xFFFF - idx) << 16) | label
// Each block owns SA=192 anchors; ballot-compacts its valid keys through an
// LDS buffer (chain length 1, LDS atomics only - r1/r4 lessons) and writes
// them to a private fixed-stride global segment + exact count. No dense
// 3.15MB key array, no separate compact kernel.
__global__ __launch_bounds__(768) void k_score(const float* __restrict__ cls,
                                               const float* __restrict__ thr_p,
                                               u64* __restrict__ cseg,
                                               unsigned* __restrict__ segcnt) {
  __shared__ __align__(16) float lds[SA * NC];   // 69120 B; kbuf overlays later
  __shared__ unsigned scnt;
  int b = blockIdx.y;
  int blk = blockIdx.x;
  int t0 = blk * SA;
  int tid = threadIdx.x;
  int lane = tid & 63;
  if (tid == 0) scnt = 0u;
  int acnt = NN - t0; if (acnt > SA) acnt = SA;
  const float4* src = (const float4*)(cls + ((size_t)b * NN + t0) * NC);
  float4* dst = (float4*)lds;
  int elems4 = acnt * NC / 4;
  for (int t = tid; t < elems4; t += 768) dst[t] = src[t];
  __syncthreads();
  int a = tid >> 2, q = tid & 3;
  float best = -1e30f; int bc = 0;
  if (a < acnt) {
    for (int c = q; c < NC; c += 4) {
      float v = lds[a * NC + c];
      if (v > best) { best = v; bc = c; }
    }
    float ov; int oc;
    ov = __shfl_xor(best, 1); oc = __shfl_xor(bc, 1);
    if (ov > best || (ov == best && oc < bc)) { best = ov; bc = oc; }
    ov = __shfl_xor(best, 2); oc = __shfl_xor(bc, 2);
    if (ov > best || (ov == best && oc < bc)) { best = ov; bc = oc; }
  }
  bool valid = (q == 0) && (a < acnt) && (best >= *thr_p);
  u64 key = 0ULL;
  if (valid) {
    unsigned idx = (unsigned)(t0 + a);
    key = ((u64)__float_as_uint(best) << 32) |
          ((u64)(0xFFFFu - idx) << 16) | (u64)(unsigned)bc;
  }
  __syncthreads();          // all lds reads finished; kbuf may overwrite
  u64* kbuf = (u64*)lds;
  u64 m = __ballot(valid);
  if (m) {
    int leader = (int)__ffsll((unsigned long long)m) - 1;
    unsigned base = 0;
    if (lane == leader) base = atomicAdd(&scnt, (unsigned)__popcll(m));
    base = __shfl(base, leader);
    if (valid) {
      unsigned pos = base + (unsigned)__popcll(m & ((1ULL << lane) - 1ULL));
      kbuf[pos] = key;      // pos < 192 guaranteed (<=192 owners/block)
    }
  }
  __syncthreads();
  unsigned cnt = scnt;
  u64* dseg = cseg + ((size_t)b * NSEG + blk) * SA;
  for (unsigned t = tid; t < cnt; t += 768) dseg[t] = kbuf[t];
  if (tid == 0) segcnt[b * NSEG + blk] = cnt;
}

__device__ __forceinline__ void decode_box(const float4 rg, const float4 an,
                                           float W, float H, float* out) {
#pragma clang fp contract(off)
  float l = an.x, t = an.y, r = an.z, bo = an.w;
  float wa = r - l, ha = bo - t;
  float cxa = l + wa * 0.5f, cya = t + ha * 0.5f;
  float cx = cxa + rg.x * wa;
  float cy = cya + rg.y * ha;
  float w = wa * expf(rg.z);
  float h = ha * expf(rg.w);
  float left = cx - w * 0.5f, top = cy - h * 0.5f;
  float right = left + w, botm = top + h;
  out[0] = fminf(fmaxf(left, 0.f), W - 1.f);
  out[1] = fminf(fmaxf(top, 0.f), H - 1.f);
  out[2] = fminf(fmaxf(right, 0.f), W - 1.f);
  out[3] = fminf(fmaxf(botm, 0.f), H - 1.f);
}

// ---- fused worker: segmented gather (scan of 256 exact counts) + counting
//      sort + tie sort + decode + per-class parallel NMS (r6-verified) ----
__global__ __launch_bounds__(1024) void k_worker(
    const u64* __restrict__ cseg, const unsigned* __restrict__ segcnt,
    const float* __restrict__ regs, const float* __restrict__ anch,
    const int* __restrict__ isz, const int* __restrict__ iszo,
    const float* __restrict__ nthr_p, float* __restrict__ out) {
#pragma clang fp contract(off)
  __shared__ __align__(16) char S[151552];
  __shared__ unsigned wsum[16];
  __shared__ unsigned segc[NSEG];
  __shared__ unsigned sofsL[NSEG + 1];
  __shared__ unsigned wcar[4];
  __shared__ int lcnt[NC];
  __shared__ int lofs[NC + 1];

  u64* cand = (u64*)S;                       // [0, 65536)
  u64* outk = (u64*)(S + 65536);             // [65536, 131072)
  unsigned* hist = (unsigned*)(S + 131072);  // [131072, 151552)

  int tid = threadIdx.x;
  int lane = tid & 63, wid = tid >> 6;
  int b = blockIdx.x;

  for (int i = tid; i < NB2P; i += 1024) hist[i] = 0u;
  if (tid < NSEG) {
    unsigned c = segcnt[b * NSEG + tid]; if (c > SA) c = SA;
    segc[tid] = c;
  }
  __syncthreads();

  // exclusive scan of 256 segment counts (4 full waves + carry)
  unsigned vv = 0;
  if (tid < NSEG) {
    vv = segc[tid];
    for (int d = 1; d < 64; d <<= 1) {
      unsigned o = __shfl_up(vv, d);
      if (lane >= d) vv += o;
    }
    if (lane == 63) wcar[wid] = vv;
  }
  __syncthreads();
  if (tid < NSEG) {
    unsigned add = 0;
    for (int w = 0; w < wid; w++) add += wcar[w];
    sofsL[tid] = add + vv - segc[tid];
    if (tid == NSEG - 1) sofsL[NSEG] = add + vv;
  }
  __syncthreads();
  unsigned total = sofsL[NSEG]; if (total > CAP2) total = CAP2;

  // gather segments into cand + fused histogram (4 threads per segment)
  {
    int s = tid >> 2, sub = tid & 3;
    unsigned c = segc[s], o = sofsL[s];
    const u64* srcp = cseg + ((size_t)b * NSEG + s) * SA;
    for (unsigned j = sub; j < c; j += 4) {
      u64 key = srcp[j];
      unsigned pos = o + j;
      if (pos < CAP2) {
        cand[pos] = key;
        unsigned bin = (0x3F800000u - (unsigned)(key >> 32) - 1u) >> 2;
        if (bin >= NB2) bin = NB2 - 1;
        atomicAdd(&hist[bin], 1u);
      }
    }
  }
  __syncthreads();

  // exclusive prefix scan: 5 bins/thread, wave scan + cross-wave scan
  int base5 = tid * 5;
  unsigned mysum = 0;
#pragma unroll
  for (int i = 0; i < 5; i++) mysum += hist[base5 + i];
  unsigned v = mysum;
  for (int d = 1; d < 64; d <<= 1) {
    unsigned o = __shfl_up(v, d);
    if (lane >= d) v += o;
  }
  if (lane == 63) wsum[wid] = v;
  __syncthreads();
  if (tid == 0) {
    unsigned acc = 0;
    for (int w2 = 0; w2 < 16; w2++) { unsigned c = wsum[w2]; wsum[w2] = acc; acc += c; }
  }
  __syncthreads();
  unsigned running = wsum[wid] + v - mysum;
#pragma unroll
  for (int i = 0; i < 5; i++) {
    unsigned c = hist[base5 + i];
    hist[base5 + i] = running;
    running += c;
  }
  __syncthreads();

  // scatter into bin slots
  for (unsigned p = tid; p < total; p += 1024) {
    u64 key = cand[p];
    unsigned bin = (0x3F800000u - (unsigned)(key >> 32) - 1u) >> 2;
    if (bin >= NB2) bin = NB2 - 1;
    unsigned pos = atomicAdd(&hist[bin], 1u);
    if (pos < CAP2) outk[pos] = key;
  }
  __syncthreads();

  // insertion sort ties within each bin (full u64 key -> deterministic order)
  for (int bin = tid; bin < NB2; bin += 1024) {
    unsigned hi = hist[bin];
    unsigned lo = bin ? hist[bin - 1] : 0u;
    if (hi > CAP2) hi = CAP2;
    if (lo > CAP2) lo = CAP2;
    if (hi > lo + 1) {
      for (unsigned i2 = lo + 1; i2 < hi; i2++) {
        u64 kx = outk[i2];
        int j = (int)i2 - 1;
        while (j >= (int)lo && outk[j] < kx) { outk[j + 1] = outk[j]; j--; }
        outk[j + 1] = kx;
      }
    }
  }
  __syncthreads();

  // ---- phase B: decode top-n + per-class NMS over overlaid LDS ----
  int n = (int)total; if (n > NK) n = NK;
  float4* bo = (float4*)S;                              // [0, 16000)
  unsigned short* llab = (unsigned short*)(S + 16000);  // [16000, 18000)
  unsigned short* sidx = (unsigned short*)(S + 18000);  // [18000, 20000)
  unsigned char* live = (unsigned char*)(S + 20000);    // [20000, 21000)
  u64* clsbits = (u64*)(S + 21008);                     // [21008, 32528) 90x16
  u64* nmsmask = (u64*)(S + 32536);                     // [32536, 78616) 90x64
  // clsbits/bo/llab/sidx/live sit in dead cand[]; nmsmask additionally
  // overlays outk[] but is only written AFTER decode consumed outk.

  float H = (float)isz[b * 2 + 0];
  float W = (float)isz[b * 2 + 1];
  float scale = (float)iszo[b * 2 + 0] / H;
  float offmul = fmaxf(W, H) + 1.0f;
  for (int i = tid; i < NC * 16; i += 1024) clsbits[i] = 0ULL;
  for (int k = tid; k < n; k += 1024) {
    u64 key = outk[k];
    float sc = __uint_as_float((unsigned)(key >> 32));
    unsigned idx = 0xFFFFu - (unsigned)((key >> 16) & 0xFFFFull);
    int lab = (int)(key & 0xFFFFull);
    float raw[4];
    float4 rg = ((const float4*)regs)[(size_t)b * NN + idx];
    float4 an = ((const float4*)anch)[idx];
    decode_box(rg, an, W, H, raw);
    float off = (float)lab * offmul;
    bo[k] = make_float4(raw[0] + off, raw[1] + off, raw[2] + off, raw[3] + off);
    llab[k] = (unsigned short)lab;
    live[k] = 1;
    int g = b * NK + k;
    float* o5 = out + (size_t)g * 5;
    o5[0] = raw[0] * scale; o5[1] = raw[1] * scale;
    o5[2] = raw[2] * scale; o5[3] = raw[3] * scale;
    o5[4] = sc;
    out[(size_t)NB * NK * 5 + g] = (float)lab;
  }
  __syncthreads();  // outk fully consumed; clsbits zeroed

  // per-class membership bitmaps (k ascending == score descending)
  for (int k = tid; k < n; k += 1024)
    atomicOr(&clsbits[(int)llab[k] * 16 + (k >> 6)], 1ULL << (k & 63));
  __syncthreads();

  // class sizes via popcount, then exclusive prefix
  if (tid < NC) {
    unsigned cnt = 0;
#pragma unroll
    for (int w = 0; w < 16; w++) cnt += (unsigned)__popcll(clsbits[tid * 16 + w]);
    lcnt[tid] = (int)cnt;
  }
  __syncthreads();
  if (tid == 0) {
    int acc = 0;
    for (int c = 0; c < NC; c++) { lofs[c] = acc; acc += lcnt[c]; }
    lofs[NC] = acc;
  }
  __syncthreads();

  // deterministic rank placement: sidx buckets sorted ascending k, no sort
  for (int k = tid; k < n; k += 1024) {
    int lab = (int)llab[k];
    const u64* cb = &clsbits[lab * 16];
    int w0 = k >> 6;
    unsigned pos = 0;
    for (int w = 0; w < w0; w++) pos += (unsigned)__popcll(cb[w]);
    pos += (unsigned)__popcll(cb[w0] & ((1ULL << (k & 63)) - 1ULL));
    sidx[lofs[lab] + pos] = (unsigned short)k;
  }
  __syncthreads();

  // pair IoU, one suppression row per thread (1024-wide parallel).
  // sidx[p] < sidx[q] for p<q in a bucket -> verbatim i<j operand order.
  float thr = *nthr_p;
  for (int p = tid; p < n; p += 1024) {
    int ki = (int)sidx[p];
    int lab = (int)llab[ki];
    int s = lofs[lab], e = lofs[lab + 1];
    int r = p - s;
    if (r < 64) {
      u64 mask = 0ULL;
      float4 Bb = bo[ki];
      float x0 = Bb.x, y0 = Bb.y, x1 = Bb.z, y1 = Bb.w;
      float ai = (x1 - x0) * (y1 - y0);
      int qe = e; if (qe > s + 64) qe = s + 64;
      for (int q = p + 1; q < qe; q++) {
        int kj = (int)sidx[q];
        float4 Cc = bo[kj];
        float aj = (Cc.z - Cc.x) * (Cc.w - Cc.y);
        float ltx = fmaxf(x0, Cc.x), lty = fmaxf(y0, Cc.y);
        float rbx = fminf(x1, Cc.z), rby = fminf(y1, Cc.w);
        float ww = fmaxf(rbx - ltx, 0.f), hh = fmaxf(rby - lty, 0.f);
        float inter = ww * hh;
        float den = ((ai + aj) - inter) + 1e-9f;
        float iou = inter / den;
        if (iou > thr) mask |= 1ULL << (q - s);
      }
      nmsmask[lab * 64 + r] = mask;   // row owned by exactly this thread
    }
  }
  __syncthreads();

  // per-class greedy chain: O(m) dependent LDS reads, register rem
  if (tid < NC) {
    int s = lofs[tid], e = lofs[tid + 1], m = e - s;
    if (m <= 64) {
      u64 rem = 0ULL;
      for (int r = 0; r < m; r++)
        if (!((rem >> r) & 1ULL)) rem |= nmsmask[tid * 64 + r];
      for (int r = 0; r < m; r++)
        live[(int)sidx[s + r]] = (unsigned char)(1ULL ^ ((rem >> r) & 1ULL));
    } else {
      // exact fallback (bucket > 64: statistically unreachable here)
      for (int r = 0; r < m; r++) live[(int)sidx[s + r]] = 1;
      for (int i = s; i < e; i++) {
        int ki = (int)sidx[i];
        if (!live[ki]) continue;
        float4 Bb = bo[ki];
        float x0 = Bb.x, y0 = Bb.y, x1 = Bb.z, y1 = Bb.w;
        float ai = (x1 - x0) * (y1 - y0);
        for (int j = i + 1; j < e; j++) {
          int kj = (int)sidx[j];
          if (!live[kj]) continue;
          float4 Cc = bo[kj];
          float aj = (Cc.z - Cc.x) * (Cc.w - Cc.y);
          float ltx = fmaxf(x0, Cc.x), lty = fmaxf(y0, Cc.y);
          float rbx = fminf(x1, Cc.z), rby = fminf(y1, Cc.w);
          float ww = fmaxf(rbx - ltx, 0.f), hh = fmaxf(rby - lty, 0.f);
          float inter = ww * hh;
          float den = ((ai + aj) - inter) + 1e-9f;
          float iou = inter / den;
          if (iou > thr) live[kj] = 0;
        }
      }
    }
  }
  __syncthreads();

  for (int k = tid; k < NK; k += 1024) {
    int g = b * NK + k;
    int keep = (k < n) ? (int)live[k] : 0;
    if (keep) {
      out[(size_t)NB * NK * 6 + g] = 1.0f;
    } else {
      float* o5 = out + (size_t)g * 5;
      o5[0] = 0.f; o5[1] = 0.f; o5[2] = 0.f; o5[3] = 0.f; o5[4] = 0.f;
      out[(size_t)NB * NK * 5 + g] = -1.0f;
      out[(size_t)NB * NK * 6 + g] = 0.0f;
    }
  }
}

extern "C" void kernel_launch(void* const* d_in, const int* in_sizes, int n_in,
                              void* d_out, int out_size, void* d_ws, size_t ws_size,
                              hipStream_t stream) {
  const float* cls = (const float*)d_in[0];
  const float* regs = (const float*)d_in[1];
  const float* anch = (const float*)d_in[2];
  const int* isz = (const int*)d_in[3];
  const int* iszo = (const int*)d_in[4];
  const float* sthr = (const float*)d_in[5];
  const float* nthr = (const float*)d_in[6];
  float* out = (float*)d_out;

  char* p = (char*)d_ws;
  auto alloc = [&](size_t bytes) {
    char* r = p;
    p += (bytes + 255) & ~(size_t)255;
    return r;
  };
  u64* cseg = (u64*)alloc((size_t)NB * NSEG * SA * 8);       // 3.15 MB
  unsigned* segcnt = (unsigned*)alloc((size_t)NB * NSEG * 4);

  hipLaunchKernelGGL(k_score, dim3(NSEG, NB), dim3(768), 0, stream,
                     cls, sthr, cseg, segcnt);
  hipLaunchKernelGGL(k_worker, dim3(NB), dim3(1024), 0, stream,
                     cseg, segcnt, regs, anch, isz, iszo, nthr, out);
}